// Round 5
// baseline (114.016 us; speedup 1.0000x reference)
//
#include <hip/hip_runtime.h>

// Chamfer distance, B=16, N=M=4096, D=3, fp32.
// d(i,j) = n_q + (n_t - 2 q.t).
// Targets pre-packed in PAIRS: group g = targets (2g,2g+1) as two float4s
// [x0,x1,y0,y1],[z0,z1,w0,w1] (w=|t|^2) feeding v_pk_fma_f32 directly.
// Per 2 targets x 1 query: 3 pk_fma + 1 min3, zero movs (4-operand first fma).
// QPL=2 queries/lane, 8-wave blocks, __launch_bounds__(512,8) -> <=64 VGPR
// -> 4 blocks/CU = 8 waves/SIMD. Half-buffer (4xfloat4) software pipeline.

#define CB 16
#define CN 4096
#define CM 4096
#define QPL 2           // queries per lane
#define WVS 8           // waves per block
#define QPB (64 * QPL)  // queries per block = 128
#define TPW (CM / WVS)  // target float4s per wave chunk = 512 (== targets)

typedef float v4f __attribute__((ext_vector_type(4)));
typedef float v2f __attribute__((ext_vector_type(2)));

__global__ __launch_bounds__(256) void pack_pairs(
    const float* __restrict__ x1, const float* __restrict__ x2,
    v4f* __restrict__ p, int pairs1, int pairs2)
{
    int i = blockIdx.x * blockDim.x + threadIdx.x;
    const float* s;
    int li;
    if (i < pairs1)               { s = x1; li = i; }
    else if (i < pairs1 + pairs2) { s = x2; li = i - pairs1; }
    else return;
    const float* r = s + 6 * li;
    float ax = r[0], ay = r[1], az = r[2];
    float bx = r[3], by = r[4], bz = r[5];
    p[2 * i]     = (v4f){ax, bx, ay, by};
    p[2 * i + 1] = (v4f){az, bz,
                         ax * ax + ay * ay + az * az,
                         bx * bx + by * by + bz * bz};
}

// One pair-group (2 targets) against one query. No movs: first fma is
// 4-operand (fresh dest), min3 folds the 2-way min into the accumulator.
__device__ __forceinline__ void grp(const v4f t0, const v4f t1,
                                    const v2f mx, const v2f my, const v2f mz,
                                    float& best)
{
    v2f d;
    asm("v_pk_fma_f32 %0, %1, %2, %3" : "=&v"(d) : "v"(mz), "v"(t1.xy), "v"(t1.zw));
    asm("v_pk_fma_f32 %0, %1, %2, %0" : "+v"(d) : "v"(my), "v"(t0.zw));
    asm("v_pk_fma_f32 %0, %1, %2, %0" : "+v"(d) : "v"(mx), "v"(t0.xy));
    asm("v_min3_f32 %0, %1, %2, %0" : "+v"(best) : "v"(d.x), "v"(d.y));
}

// grid: (CN/QPB=32, B, 2), block 512 = 8 waves. Wave w scans targets
// [w*512, (w+1)*512) for the block's 128 queries (2/lane).
__global__ __launch_bounds__(512, 8) void chamfer_min(
    const float* __restrict__ x1raw, const float* __restrict__ x2raw,
    const v4f* __restrict__ p1, const v4f* __restrict__ p2,
    float* __restrict__ out)
{
    const int dir = blockIdx.z;
    const int b   = blockIdx.y;

    // dir 0: queries=x1, targets=packed x2. dir 1: queries=x2, targets=packed x1.
    const float* __restrict__ qraw = (dir ? x2raw : x1raw) + (size_t)b * CN * 3;
    const v4f*  __restrict__  tgt  = dir ? (p1 + (size_t)b * CN) : (p2 + (size_t)b * CM);
    float* __restrict__ o = out + (dir ? ((size_t)CB * CN + (size_t)b * CM)
                                       : ((size_t)b * CN));

    const int lane = threadIdx.x & 63;
    const int wave = __builtin_amdgcn_readfirstlane(threadIdx.x >> 6);

    v2f mx2[QPL], my2[QPL], mz2[QPL];
    float nqv[QPL];
    #pragma unroll
    for (int k = 0; k < QPL; ++k) {
        int q = blockIdx.x * QPB + lane + 64 * k;
        float qx = qraw[3 * q + 0];
        float qy = qraw[3 * q + 1];
        float qz = qraw[3 * q + 2];
        mx2[k] = (v2f){-2.0f * qx, -2.0f * qx};
        my2[k] = (v2f){-2.0f * qy, -2.0f * qy};
        mz2[k] = (v2f){-2.0f * qz, -2.0f * qz};
        nqv[k] = qx * qx + qy * qy + qz * qz;
    }

    float best[QPL];
    #pragma unroll
    for (int k = 0; k < QPL; ++k) best[k] = 1e30f;

    const v4f* __restrict__ tp = tgt + wave * TPW;

    // Half = 4 float4s = 2 pair-groups = 4 targets. 128 halves total.
    v4f A0, A1, A2, A3, B0, B1, B2, B3;
    A0 = tp[0]; A1 = tp[1]; A2 = tp[2]; A3 = tp[3];

    #pragma unroll 1
    for (int h = 0; h < 128; h += 2) {
        const int jb = (h + 1) * 4;
        B0 = tp[jb]; B1 = tp[jb + 1]; B2 = tp[jb + 2]; B3 = tp[jb + 3];
        #pragma unroll
        for (int k = 0; k < QPL; ++k) {
            grp(A0, A1, mx2[k], my2[k], mz2[k], best[k]);
            grp(A2, A3, mx2[k], my2[k], mz2[k], best[k]);
        }
        const int ja = (h + 2 < 128 ? (h + 2) * 4 : 0);  // wrap avoids OOB
        A0 = tp[ja]; A1 = tp[ja + 1]; A2 = tp[ja + 2]; A3 = tp[ja + 3];
        #pragma unroll
        for (int k = 0; k < QPL; ++k) {
            grp(B0, B1, mx2[k], my2[k], mz2[k], best[k]);
            grp(B2, B3, mx2[k], my2[k], mz2[k], best[k]);
        }
    }

    __shared__ float smem[WVS][QPL][64];
    #pragma unroll
    for (int k = 0; k < QPL; ++k)
        smem[wave][k][lane] = best[k] + nqv[k];
    __syncthreads();

    if (threadIdx.x < QPB) {
        const int k = threadIdx.x >> 6;
        const int l = threadIdx.x & 63;
        float v = smem[0][k][l];
        #pragma unroll
        for (int w = 1; w < WVS; ++w)
            v = fminf(v, smem[w][k][l]);
        o[blockIdx.x * QPB + threadIdx.x] = fmaxf(v, 0.0f);
    }
}

extern "C" void kernel_launch(void* const* d_in, const int* in_sizes, int n_in,
                              void* d_out, int out_size, void* d_ws, size_t ws_size,
                              hipStream_t stream) {
    const float* x1 = (const float*)d_in[0];   // [B,N,3]
    const float* x2 = (const float*)d_in[1];   // [B,M,3]
    float* out = (float*)d_out;

    v4f* p1 = (v4f*)d_ws;                  // CB*CN float4s (packed x1)
    v4f* p2 = p1 + (size_t)CB * CN;        // CB*CM float4s (packed x2)

    const int pairs1 = CB * CN / 2;
    const int pairs2 = CB * CM / 2;
    pack_pairs<<<(pairs1 + pairs2 + 255) / 256, 256, 0, stream>>>(x1, x2, p1, pairs1, pairs2);

    dim3 grid(CN / QPB, CB, 2);
    chamfer_min<<<grid, 512, 0, stream>>>(x1, x2, p1, p2, out);
}

// Round 6
// 95.138 us; speedup vs baseline: 1.1984x; 1.1984x over previous
//
#include <hip/hip_runtime.h>

// Chamfer distance, B=16, N=M=4096, D=3, fp32. Single dispatch.
// d(i,j) = n_q + (n_t - 2 q.t).
// Each block stages half the target cloud (2048 targets) into LDS in
// pair-group format: group g = targets (2g,2g+1) as two float4s
// [x0,x1,y0,y1],[z0,z1,w0,w1] (w=|t|^2). Inner loop: ds_read_b128
// broadcast (wave-uniform -> conflict-free) + 3 v_pk_fma_f32 + 1
// v_min3_f32 per (2 targets x query). QPL=4 queries/lane amortizes each
// ds_read over 4 query chains. Two halves with re-staging barriers.

#define CB 16
#define CN 4096
#define CM 4096
#define QPL 4            // queries per lane
#define WVS 8            // waves per block (512 threads)
#define QPB (64 * QPL)   // queries per block = 256
#define HALF_T 2048      // targets staged per half
#define GRP_PW 128       // pair-groups per wave per half (2048/2/8)

typedef float v4f __attribute__((ext_vector_type(4)));
typedef float v2f __attribute__((ext_vector_type(2)));

// One pair-group (2 targets) vs one query: 3 pk_fma + 1 min3, no movs.
__device__ __forceinline__ void grp(const v4f t0, const v4f t1,
                                    const v2f mx, const v2f my, const v2f mz,
                                    float& best)
{
    v2f d;
    asm("v_pk_fma_f32 %0, %1, %2, %3" : "=&v"(d) : "v"(mz), "v"(t1.xy), "v"(t1.zw));
    asm("v_pk_fma_f32 %0, %1, %2, %0" : "+v"(d) : "v"(my), "v"(t0.zw));
    asm("v_pk_fma_f32 %0, %1, %2, %0" : "+v"(d) : "v"(mx), "v"(t0.xy));
    asm("v_min3_f32 %0, %1, %2, %0" : "+v"(best) : "v"(d.x), "v"(d.y));
}

// grid: (CN/QPB=16, B=16, 2 dirs) = 512 blocks, 512 threads = 8 waves.
__global__ __launch_bounds__(512, 4) void chamfer_min(
    const float* __restrict__ x1, const float* __restrict__ x2,
    float* __restrict__ out)
{
    const int dir = blockIdx.z;
    const int b   = blockIdx.y;

    const float* __restrict__ qraw = (dir ? x2 : x1) + (size_t)b * CN * 3;
    const float* __restrict__ traw = (dir ? x1 : x2) + (size_t)b * CM * 3;
    float* __restrict__ o = out + (dir ? ((size_t)CB * CN + (size_t)b * CM)
                                       : ((size_t)b * CN));

    __shared__ v4f tgt_lds[HALF_T * 2 / 2 * 2];  // 1024 groups x 2 v4f = 32 KB
    __shared__ float red[WVS][QPL][64];          // 8 KB

    const int tid  = threadIdx.x;
    const int lane = tid & 63;
    const int wave = __builtin_amdgcn_readfirstlane(tid >> 6);

    // Load queries (once). q = blockIdx.x*256 + lane + 64k.
    v2f mx2[QPL], my2[QPL], mz2[QPL];
    float nqv[QPL];
    #pragma unroll
    for (int k = 0; k < QPL; ++k) {
        int q = blockIdx.x * QPB + lane + 64 * k;
        float qx = qraw[3 * q + 0];
        float qy = qraw[3 * q + 1];
        float qz = qraw[3 * q + 2];
        mx2[k] = (v2f){-2.0f * qx, -2.0f * qx};
        my2[k] = (v2f){-2.0f * qy, -2.0f * qy};
        mz2[k] = (v2f){-2.0f * qz, -2.0f * qz};
        nqv[k] = qx * qx + qy * qy + qz * qz;
    }

    float best[QPL];
    #pragma unroll
    for (int k = 0; k < QPL; ++k) best[k] = 1e30f;

    #pragma unroll 1
    for (int half = 0; half < 2; ++half) {
        // ---- Stage 2048 targets: thread t packs targets [4t, 4t+4) ----
        {
            const float* r = traw + (size_t)(half * HALF_T + 4 * tid) * 3;
            const v4f* rv = (const v4f*)r;       // 48B-aligned
            v4f r0 = rv[0], r1 = rv[1], r2 = rv[2];
            // r0=(t0x,t0y,t0z,t1x) r1=(t1y,t1z,t2x,t2y) r2=(t2z,t3x,t3y,t3z)
            float w0 = r0.x * r0.x + r0.y * r0.y + r0.z * r0.z;
            float w1 = r0.w * r0.w + r1.x * r1.x + r1.y * r1.y;
            float w2 = r1.z * r1.z + r1.w * r1.w + r2.x * r2.x;
            float w3 = r2.y * r2.y + r2.z * r2.z + r2.w * r2.w;
            tgt_lds[4 * tid + 0] = (v4f){r0.x, r0.w, r0.y, r1.x};  // x0,x1,y0,y1
            tgt_lds[4 * tid + 1] = (v4f){r0.z, r1.y, w0, w1};      // z0,z1,w0,w1
            tgt_lds[4 * tid + 2] = (v4f){r1.z, r2.y, r1.w, r2.z};
            tgt_lds[4 * tid + 3] = (v4f){r2.x, r2.w, w2, w3};
        }
        __syncthreads();

        // ---- Scan: wave w handles local groups [w*128, w*128+128) ----
        const v4f* tp = &tgt_lds[wave * GRP_PW * 2];
        #pragma unroll 1
        for (int g = 0; g < GRP_PW; g += 2) {
            v4f a0 = tp[2 * g + 0];
            v4f a1 = tp[2 * g + 1];
            v4f b0 = tp[2 * g + 2];
            v4f b1 = tp[2 * g + 3];
            #pragma unroll
            for (int k = 0; k < QPL; ++k)
                grp(a0, a1, mx2[k], my2[k], mz2[k], best[k]);
            #pragma unroll
            for (int k = 0; k < QPL; ++k)
                grp(b0, b1, mx2[k], my2[k], mz2[k], best[k]);
        }
        __syncthreads();   // before next half overwrites LDS
    }

    // ---- Cross-wave min combine ----
    #pragma unroll
    for (int k = 0; k < QPL; ++k)
        red[wave][k][lane] = best[k] + nqv[k];
    __syncthreads();

    if (tid < QPB) {
        const int k = tid >> 6;
        const int l = tid & 63;
        float v = red[0][k][l];
        #pragma unroll
        for (int w = 1; w < WVS; ++w)
            v = fminf(v, red[w][k][l]);
        o[blockIdx.x * QPB + tid] = fmaxf(v, 0.0f);
    }
}

extern "C" void kernel_launch(void* const* d_in, const int* in_sizes, int n_in,
                              void* d_out, int out_size, void* d_ws, size_t ws_size,
                              hipStream_t stream) {
    const float* x1 = (const float*)d_in[0];   // [B,N,3]
    const float* x2 = (const float*)d_in[1];   // [B,M,3]
    float* out = (float*)d_out;

    dim3 grid(CN / QPB, CB, 2);
    chamfer_min<<<grid, 512, 0, stream>>>(x1, x2, out);
}